// Round 6
// baseline (323.760 us; speedup 1.0000x reference)
//
#include <hip/hip_runtime.h>

// UnigramLM forward-backward posterior, T=2048, L=8, V=32000.
// R6: 256-thread blocks (rocclr-like fill granularity); phase-1 runs 2
//     columns/thread for ILP; vectorized staging; nt 16B fill stores.
//   Kernel A: block 0 = forward scan, block 1 = backward scan,
//             blocks 2.. = 262MB zero-fill (concurrent).
//   Kernel B: scatter exp2(alpha2[t] + w2 + beta2[t+l] - alpha2[T]).

#define NEGV -1e9f
#define LOG2E 1.4426950408889634f
constexpr int T = 2048;
constexpr int L = 8;
constexpr int V = 32000;
constexpr int NCH = 64;   // chunks per scan
constexpr int K = 32;     // steps per chunk (NCH*K == T)
constexpr int BLK = 256;
constexpr int FILLB = 4096;            // fill blocks; 64,000 B each (exact)
constexpr int N4 = T * V / 4;          // 16,384,000 16B-vectors
constexpr int CH4 = N4 / FILLB;        // 4000 per fill block

typedef float vfloat4 __attribute__((ext_vector_type(4)));

__device__ __forceinline__ float hexp2(float x) { return __builtin_amdgcn_exp2f(x); }
__device__ __forceinline__ float hlog2(float x) { return __builtin_amdgcn_logf(x); }

__device__ __forceinline__ float lse8v(float t0, float t1, float t2, float t3,
                                       float t4, float t5, float t6, float t7) {
    float m = fmaxf(fmaxf(fmaxf(t0, t1), fmaxf(t2, t3)),
                    fmaxf(fmaxf(t4, t5), fmaxf(t6, t7)));
    float s = hexp2(t0 - m) + hexp2(t1 - m) + hexp2(t2 - m) + hexp2(t3 - m)
            + hexp2(t4 - m) + hexp2(t5 - m) + hexp2(t6 - m) + hexp2(t7 - m);
    return m + hlog2(s);
}

__global__ __launch_bounds__(BLK) void scan_fill_kernel(
        const float* __restrict__ logp, const int* __restrict__ midx,
        float* __restrict__ out, float* __restrict__ alpha, float* __restrict__ beta,
        float* __restrict__ wf, float* __restrict__ wb) {
    const int tid = threadIdx.x;
    const int bx = blockIdx.x;

    if (bx >= 2) {
        // ---- contiguous zero-fill, nontemporal 16B stores ----
        vfloat4 z = (vfloat4)0.f;
        vfloat4* o4 = (vfloat4*)out;
        const int base4 = (bx - 2) * CH4;
        const int end4 = base4 + CH4;
        for (int i = base4 + tid; i < end4; i += BLK)
            __builtin_nontemporal_store(z, &o4[i]);
        return;
    }

    __shared__ __align__(16) float sPm[NCH * 64];   // 16 KB: per-chunk 8x8 operators
    __shared__ float sVst[(NCH + 1) * 8];           // chunk-boundary states

    // ---- staging: w rows (log2 domain) into global scratch, float4 dest writes
    float* w = (bx == 0) ? wf : wb;
    if (bx == 0) {
        // wf[r][j] = w[r-j][j] * log2e  (NEG if r<j or no match)
        for (int oo = tid; oo < T * 2; oo += BLK) {
            int r = oo >> 1, j0 = (oo & 1) * 4;
            vfloat4 v;
#pragma unroll
            for (int u = 0; u < 4; ++u) {
                int j = j0 + u, t = r - j;
                float x = NEGV;
                if (t >= 0) { int m = midx[(t << 3) + j]; if (m >= 0) x = logp[m] * LOG2E; }
                v[u] = x;
            }
            ((vfloat4*)wf)[oo] = v;
        }
        if (tid == 0) alpha[0] = 0.f;
    } else {
        // wb[s][j] = w[T-1-s][j] * log2e
        for (int oo = tid; oo < T * 2; oo += BLK) {
            int s = oo >> 1, j0 = (oo & 1) * 4, t = T - 1 - s;
            vfloat4 v;
#pragma unroll
            for (int u = 0; u < 4; ++u) {
                int m = midx[(t << 3) + j0 + u];
                v[u] = (m >= 0) ? logp[m] * LOG2E : NEGV;
            }
            ((vfloat4*)wb)[oo] = v;
        }
        if (tid == 0) beta[T] = 0.f;
    }
    __syncthreads();

    // ---- phase 1: operator composition; thread = (chunk, colpair), 2 chains/thread
    {
        const int c = tid >> 2, sub = tid & 3;   // cols sub and sub+4
        float q0[8], q1[8];
#pragma unroll
        for (int i = 0; i < 8; ++i) {
            q0[i] = (i == sub) ? 0.f : NEGV;
            q1[i] = (i == sub + 4) ? 0.f : NEGV;
        }
        const float4* wr4 = (const float4*)(w + c * K * 8);
        float4 c0 = wr4[0], c1 = wr4[1];
        float4 b0 = wr4[2], b1 = wr4[3];
        for (int k = 0; k < K; ++k) {
            float4 a0, a1;
            if (k + 2 < K) { a0 = wr4[(k + 2) * 2]; a1 = wr4[(k + 2) * 2 + 1]; }
            float top0 = lse8v(c0.x + q0[0], c0.y + q0[1], c0.z + q0[2], c0.w + q0[3],
                               c1.x + q0[4], c1.y + q0[5], c1.z + q0[6], c1.w + q0[7]);
            float top1 = lse8v(c0.x + q1[0], c0.y + q1[1], c0.z + q1[2], c0.w + q1[3],
                               c1.x + q1[4], c1.y + q1[5], c1.z + q1[6], c1.w + q1[7]);
#pragma unroll
            for (int i = 7; i > 0; --i) { q0[i] = q0[i - 1]; q1[i] = q1[i - 1]; }
            q0[0] = top0; q1[0] = top1;
            c0 = b0; c1 = b1; b0 = a0; b1 = a1;
        }
#pragma unroll
        for (int i = 0; i < 8; ++i) {
            sPm[c * 64 + i * 8 + sub] = q0[i];
            sPm[c * 64 + i * 8 + sub + 4] = q1[i];
        }
    }
    __syncthreads();

    // ---- phase 2: sequential combine across chunks (lanes 0..7, LDS prefetch)
    if (tid < 8) {
        const int r = tid;
        float v = (r == 0) ? 0.f : NEGV;
        float4 r0 = *(const float4*)&sPm[r * 8];
        float4 r1 = *(const float4*)&sPm[r * 8 + 4];
        for (int cc = 0; cc < NCH; ++cc) {
            sVst[cc * 8 + r] = v;
            float4 n0, n1;
            if (cc + 1 < NCH) {
                n0 = *(const float4*)&sPm[(cc + 1) * 64 + r * 8];
                n1 = *(const float4*)&sPm[(cc + 1) * 64 + r * 8 + 4];
            }
            float vb0 = __shfl(v, 0, 8), vb1 = __shfl(v, 1, 8);
            float vb2 = __shfl(v, 2, 8), vb3 = __shfl(v, 3, 8);
            float vb4 = __shfl(v, 4, 8), vb5 = __shfl(v, 5, 8);
            float vb6 = __shfl(v, 6, 8), vb7 = __shfl(v, 7, 8);
            v = lse8v(r0.x + vb0, r0.y + vb1, r0.z + vb2, r0.w + vb3,
                      r1.x + vb4, r1.y + vb5, r1.z + vb6, r1.w + vb7);
            r0 = n0; r1 = n1;
        }
        sVst[NCH * 8 + r] = v;
    }
    __syncthreads();

    // ---- phase 3: re-run each chunk from its boundary state, emitting values
    if (tid < NCH) {
        const int cc = tid;
        float ab[8];
#pragma unroll
        for (int i = 0; i < 8; ++i) ab[i] = sVst[cc * 8 + i];
        const float4* wr4 = (const float4*)(w + cc * K * 8);
        float4 c0 = wr4[0], c1 = wr4[1];
        float4 b0 = wr4[2], b1 = wr4[3];
        for (int k = 0; k < K; ++k) {
            float4 a0, a1;
            if (k + 2 < K) { a0 = wr4[(k + 2) * 2]; a1 = wr4[(k + 2) * 2 + 1]; }
            float val = lse8v(c0.x + ab[0], c0.y + ab[1], c0.z + ab[2], c0.w + ab[3],
                              c1.x + ab[4], c1.y + ab[5], c1.z + ab[6], c1.w + ab[7]);
            int s = cc * K + k;
            if (bx == 0) alpha[s + 1] = val;
            else         beta[T - 1 - s] = val;
#pragma unroll
            for (int i = 7; i > 0; --i) ab[i] = ab[i - 1];
            ab[0] = val;
            c0 = b0; c1 = b1; b0 = a0; b1 = a1;
        }
    }
}

__global__ __launch_bounds__(256) void scatter_kernel(
        const float* __restrict__ logp, const int* __restrict__ midx,
        float* __restrict__ out, const float* __restrict__ alpha,
        const float* __restrict__ beta) {
    int i = blockIdx.x * blockDim.x + threadIdx.x;
    if (i >= T * L) return;
    int m = midx[i];
    if (m < 0) return;
    int t = i >> 3, j = i & 7;
    int nx = t + j + 1;
    if (nx > T) nx = T;
    float lp2 = alpha[t] + logp[m] * LOG2E + beta[nx] - alpha[T];
    atomicAdd(&out[(size_t)t * V + m], hexp2(lp2));
}

extern "C" void kernel_launch(void* const* d_in, const int* in_sizes, int n_in,
                              void* d_out, int out_size, void* d_ws, size_t ws_size,
                              hipStream_t stream) {
    const float* logp = (const float*)d_in[0];   // [V]
    const int*   midx = (const int*)d_in[1];     // [T, L]
    float* out = (float*)d_out;                  // [T, V]

    float* ws    = (float*)d_ws;
    float* alpha = ws;                 // 2049 -> pad 2064 (log2 domain)
    float* beta  = alpha + 2064;       // 2049 -> pad 2064 (log2 domain)
    float* wf    = beta + 2064;        // 16384
    float* wb    = wf + 16384;         // 16384

    scan_fill_kernel<<<dim3(2 + FILLB), BLK, 0, stream>>>(logp, midx, out, alpha, beta, wf, wb);
    scatter_kernel<<<dim3((T * L) / 256), 256, 0, stream>>>(logp, midx, out, alpha, beta);
}

// Round 7
// 286.215 us; speedup vs baseline: 1.1312x; 1.1312x over previous
//
#include <hip/hip_runtime.h>

// UnigramLM forward-backward posterior, T=2048, L=8, V=32000.
// R7: scan fully in LDS (staged w + padded layouts, coalesced final dump);
//     fill uses PLAIN float4 stores (rocclr-style; nt removed as suspect).
//   Kernel A: block 0 = forward scan, block 1 = backward scan,
//             blocks 2.. = 262MB zero-fill (concurrent).
//   Kernel B: scatter exp2(alpha2[t] + w2 + beta2[t+l] - alpha2[T]).

#define NEGV -1e9f
#define LOG2E 1.4426950408889634f
constexpr int T = 2048;
constexpr int L = 8;
constexpr int V = 32000;
constexpr int NCH = 64;   // chunks per scan
constexpr int K = 32;     // steps per chunk (NCH*K == T)
constexpr int BLK = 512;
constexpr int FILLB = 4096;            // fill blocks; 64,000 B each
constexpr int N4 = T * V / 4;          // 16,384,000 float4s
constexpr int CH4 = N4 / FILLB;        // 4000 per fill block (exact)
constexpr int CPAD = K * 8 + 4;        // 260 floats/chunk: +16B pad → phase-3
                                       // lane stride 1040B = 65x16 → 8 bank-starts

__device__ __forceinline__ float hexp2(float x) { return __builtin_amdgcn_exp2f(x); }
__device__ __forceinline__ float hlog2(float x) { return __builtin_amdgcn_logf(x); }

__device__ __forceinline__ float lse8v(float t0, float t1, float t2, float t3,
                                       float t4, float t5, float t6, float t7) {
    float m = fmaxf(fmaxf(fmaxf(t0, t1), fmaxf(t2, t3)),
                    fmaxf(fmaxf(t4, t5), fmaxf(t6, t7)));
    float s = hexp2(t0 - m) + hexp2(t1 - m) + hexp2(t2 - m) + hexp2(t3 - m)
            + hexp2(t4 - m) + hexp2(t5 - m) + hexp2(t6 - m) + hexp2(t7 - m);
    return m + hlog2(s);
}

__global__ __launch_bounds__(BLK) void scan_fill_kernel(
        const float* __restrict__ logp, const int* __restrict__ midx,
        float* __restrict__ out, float* __restrict__ alpha, float* __restrict__ beta) {
    const int tid = threadIdx.x;
    const int bx = blockIdx.x;

    if (bx >= 2) {
        // ---- contiguous zero-fill, plain 16B stores (rocclr-style) ----
        float4 z = make_float4(0.f, 0.f, 0.f, 0.f);
        float4* o4 = (float4*)out;
        const int base4 = (bx - 2) * CH4;
        const int end4 = base4 + CH4;
        for (int i = base4 + tid; i < end4; i += BLK) o4[i] = z;
        return;
    }

    __shared__ __align__(16) float sW[NCH * CPAD];   // 66,560 B staged w (log2 dom)
    __shared__ __align__(16) float sPm[NCH * 64];    // 16,384 B chunk operators
    __shared__ float sVst[(NCH + 1) * 8];            // boundary states
    __shared__ float sOut[NCH * 33];                 // 8,448 B padded emit buffer

    // ---- staging: gathers into LDS; row r lives at sW[(r>>5)*CPAD + (r&31)*8 + j]
    if (bx == 0) {
        // forward: row r holds wrev[r][j] = w[r-j][j]
        for (int o = tid; o < T * L; o += BLK) {
            int r = o >> 3, j = o & 7, t = r - j;
            float v = NEGV;
            if (t >= 0) { int m = midx[(t << 3) + j]; if (m >= 0) v = logp[m] * LOG2E; }
            sW[(r >> 5) * CPAD + (r & 31) * 8 + j] = v;
        }
    } else {
        // backward: row s holds w[T-1-s][j]
        for (int o = tid; o < T * L; o += BLK) {
            int s = o >> 3, j = o & 7, t = T - 1 - s;
            int m = midx[(t << 3) + j];
            sW[(s >> 5) * CPAD + (s & 31) * 8 + j] = (m >= 0) ? logp[m] * LOG2E : NEGV;
        }
    }
    __syncthreads();

    // ---- phase 1: operator composition; thread (c, col); 8 thr/chunk broadcast reads
    {
        const int c = tid >> 3, col = tid & 7;
        float q[8];
#pragma unroll
        for (int i = 0; i < 8; ++i) q[i] = (i == col) ? 0.f : NEGV;
        const float* wc = &sW[c * CPAD];
        float4 c0 = *(const float4*)(wc + 0), c1 = *(const float4*)(wc + 4);
        float4 b0 = *(const float4*)(wc + 8), b1 = *(const float4*)(wc + 12);
        for (int k = 0; k < K; ++k) {
            float4 a0, a1;
            if (k + 2 < K) {
                a0 = *(const float4*)(wc + (k + 2) * 8);
                a1 = *(const float4*)(wc + (k + 2) * 8 + 4);
            }
            float top = lse8v(c0.x + q[0], c0.y + q[1], c0.z + q[2], c0.w + q[3],
                              c1.x + q[4], c1.y + q[5], c1.z + q[6], c1.w + q[7]);
#pragma unroll
            for (int i = 7; i > 0; --i) q[i] = q[i - 1];
            q[0] = top;
            c0 = b0; c1 = b1; b0 = a0; b1 = a1;
        }
#pragma unroll
        for (int i = 0; i < 8; ++i) sPm[c * 64 + i * 8 + col] = q[i];
    }
    __syncthreads();

    // ---- phase 2: sequential combine across chunks (lanes 0..7, LDS prefetch)
    if (tid < 8) {
        const int r = tid;
        float v = (r == 0) ? 0.f : NEGV;
        float4 r0 = *(const float4*)&sPm[r * 8];
        float4 r1 = *(const float4*)&sPm[r * 8 + 4];
        for (int cc = 0; cc < NCH; ++cc) {
            sVst[cc * 8 + r] = v;
            float4 n0, n1;
            if (cc + 1 < NCH) {
                n0 = *(const float4*)&sPm[(cc + 1) * 64 + r * 8];
                n1 = *(const float4*)&sPm[(cc + 1) * 64 + r * 8 + 4];
            }
            float vb0 = __shfl(v, 0, 8), vb1 = __shfl(v, 1, 8);
            float vb2 = __shfl(v, 2, 8), vb3 = __shfl(v, 3, 8);
            float vb4 = __shfl(v, 4, 8), vb5 = __shfl(v, 5, 8);
            float vb6 = __shfl(v, 6, 8), vb7 = __shfl(v, 7, 8);
            v = lse8v(r0.x + vb0, r0.y + vb1, r0.z + vb2, r0.w + vb3,
                      r1.x + vb4, r1.y + vb5, r1.z + vb6, r1.w + vb7);
            r0 = n0; r1 = n1;
        }
        sVst[NCH * 8 + r] = v;
    }
    __syncthreads();

    // ---- phase 3: re-run each chunk from boundary state, emit into padded sOut
    if (tid < NCH) {
        const int cc = tid;
        float ab[8];
#pragma unroll
        for (int i = 0; i < 8; ++i) ab[i] = sVst[cc * 8 + i];
        const float* wc = &sW[cc * CPAD];
        float4 c0 = *(const float4*)(wc + 0), c1 = *(const float4*)(wc + 4);
        float4 b0 = *(const float4*)(wc + 8), b1 = *(const float4*)(wc + 12);
        for (int k = 0; k < K; ++k) {
            float4 a0, a1;
            if (k + 2 < K) {
                a0 = *(const float4*)(wc + (k + 2) * 8);
                a1 = *(const float4*)(wc + (k + 2) * 8 + 4);
            }
            float val = lse8v(c0.x + ab[0], c0.y + ab[1], c0.z + ab[2], c0.w + ab[3],
                              c1.x + ab[4], c1.y + ab[5], c1.z + ab[6], c1.w + ab[7]);
            sOut[cc * 33 + k] = val;   // bank (cc+k)%32: 2-way, free
#pragma unroll
            for (int i = 7; i > 0; --i) ab[i] = ab[i - 1];
            ab[0] = val;
            c0 = b0; c1 = b1; b0 = a0; b1 = a1;
        }
    }
    __syncthreads();

    // ---- coalesced dump of alpha / beta to global
    if (bx == 0) {
        for (int o = tid; o < T; o += BLK)
            alpha[o + 1] = sOut[(o >> 5) * 33 + (o & 31)];
        if (tid == 0) alpha[0] = 0.f;
    } else {
        for (int o = tid; o < T; o += BLK) {
            int s = T - 1 - o;   // phase3 step s emitted beta[T-1-s]
            beta[o] = sOut[(s >> 5) * 33 + (s & 31)];
        }
        if (tid == 0) beta[T] = 0.f;
    }
}

__global__ __launch_bounds__(256) void scatter_kernel(
        const float* __restrict__ logp, const int* __restrict__ midx,
        float* __restrict__ out, const float* __restrict__ alpha,
        const float* __restrict__ beta) {
    int i = blockIdx.x * blockDim.x + threadIdx.x;
    if (i >= T * L) return;
    int m = midx[i];
    if (m < 0) return;
    int t = i >> 3, j = i & 7;
    int nx = t + j + 1;
    if (nx > T) nx = T;
    float lp2 = alpha[t] + logp[m] * LOG2E + beta[nx] - alpha[T];
    atomicAdd(&out[(size_t)t * V + m], hexp2(lp2));
}

extern "C" void kernel_launch(void* const* d_in, const int* in_sizes, int n_in,
                              void* d_out, int out_size, void* d_ws, size_t ws_size,
                              hipStream_t stream) {
    const float* logp = (const float*)d_in[0];   // [V]
    const int*   midx = (const int*)d_in[1];     // [T, L]
    float* out = (float*)d_out;                  // [T, V]

    float* ws    = (float*)d_ws;
    float* alpha = ws;                 // 2049 -> pad 2064 (log2 domain)
    float* beta  = alpha + 2064;       // 2049 (log2 domain)

    scan_fill_kernel<<<dim3(2 + FILLB), BLK, 0, stream>>>(logp, midx, out, alpha, beta);
    scatter_kernel<<<dim3((T * L) / 256), 256, 0, stream>>>(logp, midx, out, alpha, beta);
}